// Round 2
// baseline (7305.611 us; speedup 1.0000x reference)
//
#include <hip/hip_runtime.h>
#include <cstdint>

#define BATCH 8
#define SEQ   2048
#define DM    768
#define DI    1536
#define DS    16
#define NL    8
#define NVOCAB 512
#define BT    (BATCH*SEQ)      // 16384
#define NCHUNK 16
#define TC    (SEQ/NCHUNK)     // 128

typedef __attribute__((ext_vector_type(8))) short bf16x8;
typedef __attribute__((ext_vector_type(4))) float f32x4;

__device__ __forceinline__ unsigned short f2bf(float f){
  unsigned int u = __float_as_uint(f);
  u += 0x7fffu + ((u >> 16) & 1u);
  return (unsigned short)(u >> 16);
}
__device__ __forceinline__ float bf2f(unsigned short s){
  return __uint_as_float(((unsigned int)s) << 16);
}
__device__ __forceinline__ float sigm(float x){ return 1.0f/(1.0f + __expf(-x)); }
__device__ __forceinline__ float siluf(float x){ return x * sigm(x); }
__device__ __forceinline__ float softplusf(float x){
  return (x > 20.0f) ? x : log1pf(__expf(x));
}

// ---------------- weight conversion ----------------
__global__ void cvt_bf16_kernel(const float4* __restrict__ in, ushort4* __restrict__ out, int n4){
  int i = blockIdx.x*256 + threadIdx.x;
  int stride = gridDim.x*256;
  for(; i<n4; i+=stride){
    float4 v = in[i];
    ushort4 o; o.x=f2bf(v.x); o.y=f2bf(v.y); o.z=f2bf(v.z); o.w=f2bf(v.w);
    out[i]=o;
  }
}

// transpose xproj_w [NL][32][DI] -> [NL][DI][32]
__global__ void xprojT_kernel(const float* __restrict__ in, float* __restrict__ out){
  int l = blockIdx.y;
  int idx = blockIdx.x*256 + threadIdx.x;   // 49152 per layer
  int s = idx & 31, d = idx >> 5;
  out[(long)l*DI*32 + idx] = in[(long)l*32*DI + (long)s*DI + d];
}

// ---------------- conditioning ----------------
__global__ __launch_bounds__(256) void cond_kernel(const int* __restrict__ emotion,
    const int* __restrict__ style, const int* __restrict__ keysig, const int* __restrict__ modei,
    const float* __restrict__ bpm, const float* __restrict__ emo_emb, const float* __restrict__ sty_emb,
    const float* __restrict__ key_emb, const float* __restrict__ mode_emb,
    const float* __restrict__ bpm_w, const float* __restrict__ bpm_b,
    const float* __restrict__ cond_w, const float* __restrict__ cond_b,
    float* __restrict__ cond_out){
  int b = blockIdx.y;
  __shared__ float vec[5*DM];
  int e = emotion[b], st = style[b], ks = keysig[b], md = modei[b];
  float bp = bpm[b];
  for(int j=threadIdx.x; j<5*DM; j+=256){
    int seg = j/DM, off = j - seg*DM;
    float v;
    if(seg==0)      v = emo_emb[e*DM+off];
    else if(seg==1) v = sty_emb[st*DM+off];
    else if(seg==2) v = key_emb[ks*DM+off];
    else if(seg==3) v = mode_emb[md*DM+off];
    else            v = bp*bpm_w[off] + bpm_b[off];
    vec[j] = v;
  }
  __syncthreads();
  int wid = threadIdx.x>>6, lane = threadIdx.x&63;
  #pragma unroll
  for(int i=0;i<4;i++){
    int dm = blockIdx.x*16 + wid*4 + i;
    const float* w = cond_w + (long)dm*(5*DM);
    float acc = 0.f;
    for(int j=lane; j<5*DM; j+=64) acc += vec[j]*w[j];
    #pragma unroll
    for(int off=32; off>0; off>>=1) acc += __shfl_xor(acc, off);
    if(lane==0) cond_out[b*DM + dm] = acc + cond_b[dm];
  }
}

// x = tok_emb[tokens] + cond + pos_emb
__global__ void embed_kernel(const int* __restrict__ tokens, const float* __restrict__ tok_emb,
    const float* __restrict__ cond, const float* __restrict__ pos_emb, float* __restrict__ x){
  int bt = blockIdx.x;
  int b = bt >> 11, t = bt & 2047;
  int tok = tokens[bt];
  const float4* te = reinterpret_cast<const float4*>(tok_emb + (long)tok*DM);
  const float4* ce = reinterpret_cast<const float4*>(cond + (long)b*DM);
  const float4* pe = reinterpret_cast<const float4*>(pos_emb + (long)t*DM);
  float4* xo = reinterpret_cast<float4*>(x + (long)bt*DM);
  int i = threadIdx.x;  // 0..191
  float4 a = te[i], c = ce[i], p = pe[i];
  xo[i] = make_float4(a.x+c.x+p.x, a.y+c.y+p.y, a.z+c.z+p.z, a.w+c.w+p.w);
}

// ---------------- layernorm -> bf16 ----------------
__global__ __launch_bounds__(256) void ln_bf16_kernel(const float* __restrict__ x,
                     const float* __restrict__ g, const float* __restrict__ bta,
                     unsigned short* __restrict__ out){
  int row  = blockIdx.x*4 + (threadIdx.x >> 6);
  int lane = threadIdx.x & 63;
  const float* xr = x + (long)row*DM;
  float4 v[3];
  float sum=0.f, sq=0.f;
  #pragma unroll
  for(int i=0;i<3;i++){
    v[i] = *reinterpret_cast<const float4*>(xr + i*256 + lane*4);
    sum += v[i].x + v[i].y + v[i].z + v[i].w;
    sq  += v[i].x*v[i].x + v[i].y*v[i].y + v[i].z*v[i].z + v[i].w*v[i].w;
  }
  #pragma unroll
  for(int off=32; off>0; off>>=1){
    sum += __shfl_xor(sum, off);
    sq  += __shfl_xor(sq , off);
  }
  float mu  = sum * (1.0f/DM);
  float var = sq  * (1.0f/DM) - mu*mu;
  float rs  = rsqrtf(var + 1e-5f);
  unsigned short* orow = out + (long)row*DM;
  #pragma unroll
  for(int i=0;i<3;i++){
    int d = i*256 + lane*4;
    float4 gg = *reinterpret_cast<const float4*>(g + d);
    float4 bb = *reinterpret_cast<const float4*>(bta + d);
    ushort4 o;
    o.x = f2bf((v[i].x - mu)*rs*gg.x + bb.x);
    o.y = f2bf((v[i].y - mu)*rs*gg.y + bb.y);
    o.z = f2bf((v[i].z - mu)*rs*gg.z + bb.z);
    o.w = f2bf((v[i].w - mu)*rs*gg.w + bb.w);
    *reinterpret_cast<ushort4*>(orow + d) = o;
  }
}

// ---------------- GEMM: C[M,N] = A[M,K](bf16) * B[N,K](bf16)^T ----------------
// MODE 0: f32 C = acc ; MODE 1: f32 C += acc ; MODE 2: f32 C = acc + bias[col] ; MODE 3: bf16 C = acc
template<int MODE>
__global__ __launch_bounds__(256) void gemm_xwt(const unsigned short* __restrict__ A,
                                               const unsigned short* __restrict__ B,
                                               void* __restrict__ Cv,
                                               const float* __restrict__ bias,
                                               int K, int ldc){
  const short* Ap = (const short*)A;
  const short* Bp = (const short*)B;
  int lane = threadIdx.x & 63;
  int wid  = threadIdx.x >> 6;
  int r    = lane & 15;
  int kk   = (lane >> 4) << 3;      // 0,8,16,24
  int row0 = blockIdx.y*128 + (wid>>1)*64;
  int col0 = blockIdx.x*128 + (wid&1)*64;

  f32x4 acc[4][4];
  #pragma unroll
  for(int m=0;m<4;m++)
    #pragma unroll
    for(int n=0;n<4;n++)
      acc[m][n] = (f32x4){0.f,0.f,0.f,0.f};

  for(int k=0;k<K;k+=32){
    bf16x8 av[4], bv[4];
    #pragma unroll
    for(int m=0;m<4;m++)
      av[m] = *reinterpret_cast<const bf16x8*>(Ap + (long)(row0 + m*16 + r)*K + k + kk);
    #pragma unroll
    for(int n=0;n<4;n++)
      bv[n] = *reinterpret_cast<const bf16x8*>(Bp + (long)(col0 + n*16 + r)*K + k + kk);
    #pragma unroll
    for(int m=0;m<4;m++)
      #pragma unroll
      for(int n=0;n<4;n++)
        acc[m][n] = __builtin_amdgcn_mfma_f32_16x16x32_bf16(av[m], bv[n], acc[m][n], 0, 0, 0);
  }

  int rr = (lane >> 4) << 2;
  int cc = lane & 15;
  #pragma unroll
  for(int m=0;m<4;m++){
    #pragma unroll
    for(int n=0;n<4;n++){
      int col = col0 + n*16 + cc;
      #pragma unroll
      for(int i=0;i<4;i++){
        long idx = (long)(row0 + m*16 + rr + i)*ldc + col;
        float v = acc[m][n][i];
        if(MODE==3)      ((unsigned short*)Cv)[idx] = f2bf(v);
        else if(MODE==1) ((float*)Cv)[idx] += v;
        else if(MODE==2) ((float*)Cv)[idx] = v + bias[col];
        else             ((float*)Cv)[idx] = v;
      }
    }
  }
}

// ---------------- fused conv+silu+xproj: xz(bf16) -> dtb_raw [BT,32](f32) ----------------
__global__ __launch_bounds__(256) void xproj_kernel(const unsigned short* __restrict__ xz,
      const float* __restrict__ cw, const float* __restrict__ wT,
      float* __restrict__ dtb){
  __shared__ unsigned short xcs[16][DI];   // 48 KiB
  int blk = blockIdx.x;
  int b  = blk >> 7;
  int t0 = (blk & 127) << 4;
  int tid = threadIdx.x;
  long base = ((long)b*SEQ + t0)*(2*DI);
  #pragma unroll
  for(int db=0; db<6; db++){
    int d = db*256 + tid;
    float c0 = cw[d*4+0], c1 = cw[d*4+1], c2 = cw[d*4+2], c3 = cw[d*4+3];
    float wm3 = (t0>0) ? bf2f(xz[base - 3*(2*DI) + d]) : 0.f;
    float wm2 = (t0>0) ? bf2f(xz[base - 2*(2*DI) + d]) : 0.f;
    float wm1 = (t0>0) ? bf2f(xz[base - 1*(2*DI) + d]) : 0.f;
    for(int tt=0; tt<16; tt++){
      float wt = bf2f(xz[base + (long)tt*(2*DI) + d]);
      float u = c0*wm3 + c1*wm2 + c2*wm1 + c3*wt;
      xcs[tt][d] = f2bf(siluf(u));
      wm3 = wm2; wm2 = wm1; wm1 = wt;
    }
  }
  __syncthreads();
  int s   = tid & 31;
  int tt0 = tid >> 5;
  #pragma unroll
  for(int half=0; half<2; half++){
    int tt = tt0 + half*8;
    float acc = 0.f;
    for(int d=0; d<DI; d++)
      acc += bf2f(xcs[tt][d]) * wT[d*32 + s];
    dtb[((long)b*SEQ + t0 + tt)*32 + s] = acc;
  }
}

// ---------------- scan pass A: per-chunk (P = prod(1-delta), S = local h) ----------------
__global__ __launch_bounds__(256) void scanA_kernel(const unsigned short* __restrict__ xz,
      const float* __restrict__ dtb, const float* __restrict__ cw,
      const float* __restrict__ dtw_g, const float* __restrict__ dtbias_g,
      const float* __restrict__ bpw_g, float2* __restrict__ chunk){
  int c = blockIdx.x, db = blockIdx.y, b = blockIdx.z;
  int d = db*256 + threadIdx.x;
  float c0=cw[d*4],c1=cw[d*4+1],c2=cw[d*4+2],c3=cw[d*4+3];
  float dtw[16], bpw[16];
  #pragma unroll
  for(int s=0;s<16;s++){ dtw[s]=dtw_g[d*16+s]; bpw[s]=bpw_g[d*16+s]; }
  float bias = dtbias_g[d];
  int t0 = c*TC;
  long base = ((long)b*SEQ + t0)*(2*DI) + d;
  float wm3 = (t0>0) ? bf2f(xz[base - 3*(2*DI)]) : 0.f;
  float wm2 = (t0>0) ? bf2f(xz[base - 2*(2*DI)]) : 0.f;
  float wm1 = (t0>0) ? bf2f(xz[base - 1*(2*DI)]) : 0.f;
  const float4* dr = reinterpret_cast<const float4*>(dtb + ((long)b*SEQ + t0)*32);
  const unsigned short* xp = xz + base;
  float h = 0.f, P = 1.f;
  for(int t=0;t<TC;t++){
    float wt = bf2f(*xp); xp += 2*DI;
    float u = siluf(c0*wm3 + c1*wm2 + c2*wm1 + c3*wt);
    wm3=wm2; wm2=wm1; wm1=wt;
    float4 q0=dr[t*8+0], q1=dr[t*8+1], q2=dr[t*8+2], q3=dr[t*8+3];
    float4 p0=dr[t*8+4], p1=dr[t*8+5], p2=dr[t*8+6], p3=dr[t*8+7];
    float da = bias
      + q0.x*dtw[0]+q0.y*dtw[1]+q0.z*dtw[2]+q0.w*dtw[3]
      + q1.x*dtw[4]+q1.y*dtw[5]+q1.z*dtw[6]+q1.w*dtw[7]
      + q2.x*dtw[8]+q2.y*dtw[9]+q2.z*dtw[10]+q2.w*dtw[11]
      + q3.x*dtw[12]+q3.y*dtw[13]+q3.z*dtw[14]+q3.w*dtw[15];
    float ba =
        p0.x*bpw[0]+p0.y*bpw[1]+p0.z*bpw[2]+p0.w*bpw[3]
      + p1.x*bpw[4]+p1.y*bpw[5]+p1.z*bpw[6]+p1.w*bpw[7]
      + p2.x*bpw[8]+p2.y*bpw[9]+p2.z*bpw[10]+p2.w*bpw[11]
      + p3.x*bpw[12]+p3.y*bpw[13]+p3.z*bpw[14]+p3.w*bpw[15];
    float delta = fminf(fmaxf(softplusf(da), 1e-4f), 1.0f);
    float a = 1.0f - delta;
    h = h*a + u*ba;
    P *= a;
  }
  chunk[((long)b*DI + d)*NCHUNK + c] = make_float2(P, h);
}

// ---------------- scan pass C: combine chunk prefixes, emit y = (h + dp*u)*silu(z) (bf16) ----------------
__global__ __launch_bounds__(256) void scanC_kernel(const unsigned short* __restrict__ xz,
      const float* __restrict__ dtb, const float* __restrict__ cw,
      const float* __restrict__ dtw_g, const float* __restrict__ dtbias_g,
      const float* __restrict__ bpw_g, const float* __restrict__ dp_g,
      const float2* __restrict__ chunk, unsigned short* __restrict__ y){
  int c = blockIdx.x, db = blockIdx.y, b = blockIdx.z;
  int d = db*256 + threadIdx.x;
  float c0=cw[d*4],c1=cw[d*4+1],c2=cw[d*4+2],c3=cw[d*4+3];
  float dtw[16], bpw[16];
  #pragma unroll
  for(int s=0;s<16;s++){ dtw[s]=dtw_g[d*16+s]; bpw[s]=bpw_g[d*16+s]; }
  float bias = dtbias_g[d];
  float dp = dp_g[d];
  int t0 = c*TC;
  long base = ((long)b*SEQ + t0)*(2*DI) + d;
  float wm3 = (t0>0) ? bf2f(xz[base - 3*(2*DI)]) : 0.f;
  float wm2 = (t0>0) ? bf2f(xz[base - 2*(2*DI)]) : 0.f;
  float wm1 = (t0>0) ? bf2f(xz[base - 1*(2*DI)]) : 0.f;
  const float4* dr = reinterpret_cast<const float4*>(dtb + ((long)b*SEQ + t0)*32);
  const unsigned short* xp = xz + base;
  const unsigned short* zp = xz + base + DI;
  unsigned short* yp = y + ((long)b*SEQ + t0)*DI + d;
  float h = 0.f;
  const float2* cb = chunk + ((long)b*DI + d)*NCHUNK;
  for(int cc2=0; cc2<c; cc2++){ float2 ps = cb[cc2]; h = ps.x*h + ps.y; }
  for(int t=0;t<TC;t++){
    float wt = bf2f(*xp); xp += 2*DI;
    float u = siluf(c0*wm3 + c1*wm2 + c2*wm1 + c3*wt);
    wm3=wm2; wm2=wm1; wm1=wt;
    float4 q0=dr[t*8+0], q1=dr[t*8+1], q2=dr[t*8+2], q3=dr[t*8+3];
    float4 p0=dr[t*8+4], p1=dr[t*8+5], p2=dr[t*8+6], p3=dr[t*8+7];
    float da = bias
      + q0.x*dtw[0]+q0.y*dtw[1]+q0.z*dtw[2]+q0.w*dtw[3]
      + q1.x*dtw[4]+q1.y*dtw[5]+q1.z*dtw[6]+q1.w*dtw[7]
      + q2.x*dtw[8]+q2.y*dtw[9]+q2.z*dtw[10]+q2.w*dtw[11]
      + q3.x*dtw[12]+q3.y*dtw[13]+q3.z*dtw[14]+q3.w*dtw[15];
    float ba =
        p0.x*bpw[0]+p0.y*bpw[1]+p0.z*bpw[2]+p0.w*bpw[3]
      + p1.x*bpw[4]+p1.y*bpw[5]+p1.z*bpw[6]+p1.w*bpw[7]
      + p2.x*bpw[8]+p2.y*bpw[9]+p2.z*bpw[10]+p2.w*bpw[11]
      + p3.x*bpw[12]+p3.y*bpw[13]+p3.z*bpw[14]+p3.w*bpw[15];
    float delta = fminf(fmaxf(softplusf(da), 1e-4f), 1.0f);
    h = h*(1.0f - delta) + u*ba;
    float zv = bf2f(*zp); zp += 2*DI;
    float yv = (h + dp*u) * siluf(zv);
    *yp = f2bf(yv); yp += DI;
  }
}

// ---------------- launch ----------------
extern "C" void kernel_launch(void* const* d_in, const int* in_sizes, int n_in,
                              void* d_out, int out_size, void* d_ws, size_t ws_size,
                              hipStream_t stream){
  const int*   tokens  = (const int*)  d_in[0];
  const int*   emotion = (const int*)  d_in[1];
  const int*   style   = (const int*)  d_in[2];
  const int*   keysig  = (const int*)  d_in[3];
  const int*   modei   = (const int*)  d_in[4];
  const float* bpm     = (const float*)d_in[5];
  const float* tok_emb = (const float*)d_in[6];
  const float* emo_emb = (const float*)d_in[7];
  const float* sty_emb = (const float*)d_in[8];
  const float* key_emb = (const float*)d_in[9];
  const float* mode_emb= (const float*)d_in[10];
  const float* bpm_w   = (const float*)d_in[11];
  const float* bpm_b   = (const float*)d_in[12];
  const float* cond_w  = (const float*)d_in[13];
  const float* cond_b  = (const float*)d_in[14];
  const float* pos_emb = (const float*)d_in[15];
  const float* ln_g    = (const float*)d_in[16];
  const float* ln_b    = (const float*)d_in[17];
  const float* in_w    = (const float*)d_in[18];
  const float* conv_w  = (const float*)d_in[19];
  const float* xproj_w = (const float*)d_in[20];
  const float* dt_w    = (const float*)d_in[21];
  const float* dt_b    = (const float*)d_in[22];
  const float* bproj_w = (const float*)d_in[23];
  const float* d_param = (const float*)d_in[24];
  const float* out_w   = (const float*)d_in[25];
  const float* final_g = (const float*)d_in[26];
  const float* final_b = (const float*)d_in[27];
  const float* head_w  = (const float*)d_in[28];
  const float* head_b  = (const float*)d_in[29];

  // workspace layout (total 214,458,368 B ~= 204.5 MiB)
  char* ws = (char*)d_ws;
  float*          x       = (float*)(ws + 0L);                    //  50,331,648
  unsigned short* hy      = (unsigned short*)(ws + 50331648L);    //  50,331,648 (h_bf / y_bf / xfin union)
  unsigned short* xz      = (unsigned short*)(ws + 100663296L);   // 100,663,296 (bf16 [BT, 2*DI])
  float*          dtbuf   = (float*)(ws + 201326592L);            //   2,097,152
  float2*         chunk   = (float2*)(ws + 203423744L);           //   1,572,864
  float*          condv   = (float*)(ws + 204996608L);            //      24,576
  unsigned short* inwb    = (unsigned short*)(ws + 205021184L);   //   4,718,592 (per-layer)
  unsigned short* outwb   = (unsigned short*)(ws + 209739776L);   //   2,359,296 (per-layer)
  unsigned short* headwb  = (unsigned short*)(ws + 212099072L);   //     786,432
  float*          xprojT  = (float*)(ws + 212885504L);            //   1,572,864

  unsigned short* h_bf = hy;        // [BT, DM]
  unsigned short* y_bf = hy;        // [BT, DI] (reuses same region after h consumed)
  unsigned short* xfin = hy;        // [BT, DM] final LN output

  cvt_bf16_kernel<<<128,256,0,stream>>>((const float4*)head_w,(ushort4*)headwb, NVOCAB*DM/4);
  xprojT_kernel<<<dim3(192,8),256,0,stream>>>(xproj_w, xprojT);
  cond_kernel<<<dim3(48,8),256,0,stream>>>(emotion, style, keysig, modei, bpm, emo_emb, sty_emb,
        key_emb, mode_emb, bpm_w, bpm_b, cond_w, cond_b, condv);
  embed_kernel<<<BT,192,0,stream>>>(tokens, tok_emb, condv, pos_emb, x);

  for(int l=0; l<NL; l++){
    cvt_bf16_kernel<<<1024,256,0,stream>>>((const float4*)(in_w  + (long)l*2*DI*DM), (ushort4*)inwb,  2*DI*DM/4);
    cvt_bf16_kernel<<<512, 256,0,stream>>>((const float4*)(out_w + (long)l*DM*DI),   (ushort4*)outwb, DM*DI/4);
    ln_bf16_kernel<<<BT/4,256,0,stream>>>(x, ln_g + l*DM, ln_b + l*DM, h_bf);
    gemm_xwt<3><<<dim3(2*DI/128, BT/128),256,0,stream>>>(h_bf, inwb, xz, nullptr, DM, 2*DI);
    xproj_kernel<<<BT/16,256,0,stream>>>(xz, conv_w + l*DI*4, xprojT + l*DI*32, dtbuf);
    scanA_kernel<<<dim3(NCHUNK,6,BATCH),256,0,stream>>>(xz, dtbuf, conv_w + l*DI*4,
          dt_w + l*DI*DS, dt_b + l*DI, bproj_w + l*DI*DS, chunk);
    scanC_kernel<<<dim3(NCHUNK,6,BATCH),256,0,stream>>>(xz, dtbuf, conv_w + l*DI*4,
          dt_w + l*DI*DS, dt_b + l*DI, bproj_w + l*DI*DS, d_param + l*DI, chunk, y_bf);
    gemm_xwt<1><<<dim3(DM/128, BT/128),256,0,stream>>>(y_bf, outwb, x, nullptr, DI, DM);
  }
  ln_bf16_kernel<<<BT/4,256,0,stream>>>(x, final_g, final_b, xfin);
  gemm_xwt<2><<<dim3(NVOCAB/128, BT/128),256,0,stream>>>(xfin, headwb, d_out, head_b, DM, NVOCAB);
}

// Round 3
// 4986.333 us; speedup vs baseline: 1.4651x; 1.4651x over previous
//
#include <hip/hip_runtime.h>
#include <cstdint>

#define BATCH 8
#define SEQ   2048
#define DM    768
#define DI    1536
#define DS    16
#define NL    8
#define NVOCAB 512
#define BT    (BATCH*SEQ)      // 16384
#define NCHUNK 16
#define TC    (SEQ/NCHUNK)     // 128

typedef __attribute__((ext_vector_type(8))) short bf16x8;
typedef __attribute__((ext_vector_type(4))) float f32x4;

__device__ __forceinline__ unsigned short f2bf(float f){
  unsigned int u = __float_as_uint(f);
  u += 0x7fffu + ((u >> 16) & 1u);
  return (unsigned short)(u >> 16);
}
__device__ __forceinline__ float bf2f(unsigned short s){
  return __uint_as_float(((unsigned int)s) << 16);
}
__device__ __forceinline__ float sigm(float x){ return 1.0f/(1.0f + __expf(-x)); }
__device__ __forceinline__ float siluf(float x){ return x * sigm(x); }
__device__ __forceinline__ float softplusf(float x){
  return (x > 20.0f) ? x : log1pf(__expf(x));
}
__device__ __forceinline__ void async16(void* l, const void* g){
  __builtin_amdgcn_global_load_lds(
      (const __attribute__((address_space(1))) unsigned int*)g,
      (__attribute__((address_space(3))) unsigned int*)l, 16, 0, 0);
}

// ---------------- weight conversion ----------------
__global__ void cvt_bf16_kernel(const float4* __restrict__ in, ushort4* __restrict__ out, int n4){
  int i = blockIdx.x*256 + threadIdx.x;
  int stride = gridDim.x*256;
  for(; i<n4; i+=stride){
    float4 v = in[i];
    ushort4 o; o.x=f2bf(v.x); o.y=f2bf(v.y); o.z=f2bf(v.z); o.w=f2bf(v.w);
    out[i]=o;
  }
}

// ---------------- conditioning ----------------
__global__ __launch_bounds__(256) void cond_kernel(const int* __restrict__ emotion,
    const int* __restrict__ style, const int* __restrict__ keysig, const int* __restrict__ modei,
    const float* __restrict__ bpm, const float* __restrict__ emo_emb, const float* __restrict__ sty_emb,
    const float* __restrict__ key_emb, const float* __restrict__ mode_emb,
    const float* __restrict__ bpm_w, const float* __restrict__ bpm_b,
    const float* __restrict__ cond_w, const float* __restrict__ cond_b,
    float* __restrict__ cond_out){
  int b = blockIdx.y;
  __shared__ float vec[5*DM];
  int e = emotion[b], st = style[b], ks = keysig[b], md = modei[b];
  float bp = bpm[b];
  for(int j=threadIdx.x; j<5*DM; j+=256){
    int seg = j/DM, off = j - seg*DM;
    float v;
    if(seg==0)      v = emo_emb[e*DM+off];
    else if(seg==1) v = sty_emb[st*DM+off];
    else if(seg==2) v = key_emb[ks*DM+off];
    else if(seg==3) v = mode_emb[md*DM+off];
    else            v = bp*bpm_w[off] + bpm_b[off];
    vec[j] = v;
  }
  __syncthreads();
  int wid = threadIdx.x>>6, lane = threadIdx.x&63;
  #pragma unroll
  for(int i=0;i<4;i++){
    int dm = blockIdx.x*16 + wid*4 + i;
    const float* w = cond_w + (long)dm*(5*DM);
    float acc = 0.f;
    for(int j=lane; j<5*DM; j+=64) acc += vec[j]*w[j];
    #pragma unroll
    for(int off=32; off>0; off>>=1) acc += __shfl_xor(acc, off);
    if(lane==0) cond_out[b*DM + dm] = acc + cond_b[dm];
  }
}

// x = tok_emb[tokens] + cond + pos_emb
__global__ void embed_kernel(const int* __restrict__ tokens, const float* __restrict__ tok_emb,
    const float* __restrict__ cond, const float* __restrict__ pos_emb, float* __restrict__ x){
  int bt = blockIdx.x;
  int b = bt >> 11, t = bt & 2047;
  int tok = tokens[bt];
  const float4* te = reinterpret_cast<const float4*>(tok_emb + (long)tok*DM);
  const float4* ce = reinterpret_cast<const float4*>(cond + (long)b*DM);
  const float4* pe = reinterpret_cast<const float4*>(pos_emb + (long)t*DM);
  float4* xo = reinterpret_cast<float4*>(x + (long)bt*DM);
  int i = threadIdx.x;  // 0..191
  float4 a = te[i], c = ce[i], p = pe[i];
  xo[i] = make_float4(a.x+c.x+p.x, a.y+c.y+p.y, a.z+c.z+p.z, a.w+c.w+p.w);
}

// ---------------- layernorm -> bf16 ----------------
__global__ __launch_bounds__(256) void ln_bf16_kernel(const float* __restrict__ x,
                     const float* __restrict__ g, const float* __restrict__ bta,
                     unsigned short* __restrict__ out){
  int row  = blockIdx.x*4 + (threadIdx.x >> 6);
  int lane = threadIdx.x & 63;
  const float* xr = x + (long)row*DM;
  float4 v[3];
  float sum=0.f, sq=0.f;
  #pragma unroll
  for(int i=0;i<3;i++){
    v[i] = *reinterpret_cast<const float4*>(xr + i*256 + lane*4);
    sum += v[i].x + v[i].y + v[i].z + v[i].w;
    sq  += v[i].x*v[i].x + v[i].y*v[i].y + v[i].z*v[i].z + v[i].w*v[i].w;
  }
  #pragma unroll
  for(int off=32; off>0; off>>=1){
    sum += __shfl_xor(sum, off);
    sq  += __shfl_xor(sq , off);
  }
  float mu  = sum * (1.0f/DM);
  float var = sq  * (1.0f/DM) - mu*mu;
  float rs  = rsqrtf(var + 1e-5f);
  unsigned short* orow = out + (long)row*DM;
  #pragma unroll
  for(int i=0;i<3;i++){
    int d = i*256 + lane*4;
    float4 gg = *reinterpret_cast<const float4*>(g + d);
    float4 bb = *reinterpret_cast<const float4*>(bta + d);
    ushort4 o;
    o.x = f2bf((v[i].x - mu)*rs*gg.x + bb.x);
    o.y = f2bf((v[i].y - mu)*rs*gg.y + bb.y);
    o.z = f2bf((v[i].z - mu)*rs*gg.z + bb.z);
    o.w = f2bf((v[i].w - mu)*rs*gg.w + bb.w);
    *reinterpret_cast<ushort4*>(orow + d) = o;
  }
}

// ---------------- LDS-staged GEMM (m97 structure): C[M,N] = A[M,K](bf16) * B[N,K](bf16)^T
// MODE 0: f32 C = acc ; MODE 1: f32 C += acc ; MODE 2: f32 C = acc + bias[col] ; MODE 3: bf16 C = acc
template<int MODE>
__global__ __launch_bounds__(256) void gemm_lds(const unsigned short* __restrict__ A,
                                               const unsigned short* __restrict__ B,
                                               void* __restrict__ Cv,
                                               const float* __restrict__ bias,
                                               int K, int ldc){
  __shared__ short As[128*32];   // 8 KiB
  __shared__ short Bs[128*32];   // 8 KiB
  const short* Ap = (const short*)A;
  const short* Bp = (const short*)B;
  int tid  = threadIdx.x;
  int lane = tid & 63;
  int wid  = tid >> 6;
  int row0 = blockIdx.y*128;
  int col0 = blockIdx.x*128;

  // staging: 512 chunks of 16B per matrix; chunk = j*256 + tid, r=chunk>>2, c=(chunk&3)*8
  int ar = tid >> 2;
  int ac = (tid & 3) * 8;
  const short* Ag0 = Ap + (long)(row0 + ar     )*K + ac;
  const short* Ag1 = Ap + (long)(row0 + ar + 64)*K + ac;
  const short* Bg0 = Bp + (long)(col0 + ar     )*K + ac;
  const short* Bg1 = Bp + (long)(col0 + ar + 64)*K + ac;
  char* lA0 = (char*)As + tid*16;
  char* lA1 = (char*)As + (256 + tid)*16;
  char* lB0 = (char*)Bs + tid*16;
  char* lB1 = (char*)Bs + (256 + tid)*16;

  int wr = (wid>>1)*64;
  int wc = (wid&1)*64;
  int fr = lane & 15;
  int fk = (lane >> 4) << 3;

  f32x4 acc[4][4];
  #pragma unroll
  for(int m=0;m<4;m++)
    #pragma unroll
    for(int n=0;n<4;n++)
      acc[m][n] = (f32x4){0.f,0.f,0.f,0.f};

  for(int kt=0; kt<K; kt+=32){
    async16(lA0, Ag0 + kt);
    async16(lA1, Ag1 + kt);
    async16(lB0, Bg0 + kt);
    async16(lB1, Bg1 + kt);
    __syncthreads();           // compiler drains vmcnt before barrier
    bf16x8 av[4], bv[4];
    #pragma unroll
    for(int m=0;m<4;m++)
      av[m] = *reinterpret_cast<const bf16x8*>(As + (wr + m*16 + fr)*32 + fk);
    #pragma unroll
    for(int n=0;n<4;n++)
      bv[n] = *reinterpret_cast<const bf16x8*>(Bs + (wc + n*16 + fr)*32 + fk);
    #pragma unroll
    for(int m=0;m<4;m++)
      #pragma unroll
      for(int n=0;n<4;n++)
        acc[m][n] = __builtin_amdgcn_mfma_f32_16x16x32_bf16(av[m], bv[n], acc[m][n], 0, 0, 0);
    __syncthreads();           // protect LDS before next stage
  }

  int rr = (lane >> 4) << 2;
  int cc = lane & 15;
  #pragma unroll
  for(int m=0;m<4;m++){
    #pragma unroll
    for(int n=0;n<4;n++){
      int col = col0 + wc + n*16 + cc;
      #pragma unroll
      for(int i=0;i<4;i++){
        long idx = (long)(row0 + wr + m*16 + rr + i)*ldc + col;
        float v = acc[m][n][i];
        if(MODE==3)      ((unsigned short*)Cv)[idx] = f2bf(v);
        else if(MODE==1) ((float*)Cv)[idx] += v;
        else if(MODE==2) ((float*)Cv)[idx] = v + bias[col];
        else             ((float*)Cv)[idx] = v;
      }
    }
  }
}

// ---------------- fused conv+silu+xproj: xz(bf16) -> dtb_raw [BT,32](f32) ----------------
// wbf: bf16 xproj weights in ORIGINAL layout [32][DI] (row-contiguous in d)
__global__ __launch_bounds__(256) void xproj_kernel(const unsigned short* __restrict__ xz,
      const float* __restrict__ cw, const unsigned short* __restrict__ wbf,
      float* __restrict__ dtb){
  __shared__ unsigned short xcs[16][DI];   // 48 KiB
  int blk = blockIdx.x;
  int b  = blk >> 7;
  int t0 = (blk & 127) << 4;
  int tid = threadIdx.x;
  long base = ((long)b*SEQ + t0)*(2*DI);
  if(tid < 192){
    int d0 = tid*8;
    float cc0[8], cc1[8], cc2[8], cc3[8];
    #pragma unroll
    for(int j=0;j<8;j++){
      cc0[j]=cw[(d0+j)*4+0]; cc1[j]=cw[(d0+j)*4+1];
      cc2[j]=cw[(d0+j)*4+2]; cc3[j]=cw[(d0+j)*4+3];
    }
    float wm3[8], wm2[8], wm1[8];
    #pragma unroll
    for(int j=0;j<8;j++){ wm3[j]=0.f; wm2[j]=0.f; wm1[j]=0.f; }
    if(t0>0){
      bf16x8 v3 = *reinterpret_cast<const bf16x8*>(xz + base - 3*(2*DI) + d0);
      bf16x8 v2 = *reinterpret_cast<const bf16x8*>(xz + base - 2*(2*DI) + d0);
      bf16x8 v1 = *reinterpret_cast<const bf16x8*>(xz + base - 1*(2*DI) + d0);
      #pragma unroll
      for(int j=0;j<8;j++){
        wm3[j]=bf2f((unsigned short)v3[j]);
        wm2[j]=bf2f((unsigned short)v2[j]);
        wm1[j]=bf2f((unsigned short)v1[j]);
      }
    }
    for(int tt=0; tt<16; tt++){
      bf16x8 vt = *reinterpret_cast<const bf16x8*>(xz + base + (long)tt*(2*DI) + d0);
      bf16x8 o;
      #pragma unroll
      for(int j=0;j<8;j++){
        float wt = bf2f((unsigned short)vt[j]);
        float u  = cc0[j]*wm3[j] + cc1[j]*wm2[j] + cc2[j]*wm1[j] + cc3[j]*wt;
        o[j] = (short)f2bf(siluf(u));
        wm3[j]=wm2[j]; wm2[j]=wm1[j]; wm1[j]=wt;
      }
      *reinterpret_cast<bf16x8*>(&xcs[tt][d0]) = o;
    }
  }
  __syncthreads();
  int s  = tid & 31;
  int th = tid >> 5;     // 0..7 -> rows th and th+8
  const unsigned short* wrow = wbf + (long)s*DI;
  float acc0 = 0.f, acc1 = 0.f;
  for(int dc=0; dc<DI; dc+=8){
    bf16x8 w8 = *reinterpret_cast<const bf16x8*>(wrow + dc);
    bf16x8 a0 = *reinterpret_cast<const bf16x8*>(&xcs[th][dc]);
    bf16x8 a1 = *reinterpret_cast<const bf16x8*>(&xcs[th+8][dc]);
    #pragma unroll
    for(int j=0;j<8;j++){
      float wv = bf2f((unsigned short)w8[j]);
      acc0 += bf2f((unsigned short)a0[j])*wv;
      acc1 += bf2f((unsigned short)a1[j])*wv;
    }
  }
  dtb[((long)b*SEQ + t0 + th    )*32 + s] = acc0;
  dtb[((long)b*SEQ + t0 + th + 8)*32 + s] = acc1;
}

// ---------------- scan pass A: per-chunk (P = prod(1-delta), S = local h) ----------------
__global__ __launch_bounds__(256) void scanA_kernel(const unsigned short* __restrict__ xz,
      const float* __restrict__ dtb, const float* __restrict__ cw,
      const float* __restrict__ dtw_g, const float* __restrict__ dtbias_g,
      const float* __restrict__ bpw_g, float2* __restrict__ chunk){
  int c = blockIdx.x, db = blockIdx.y, b = blockIdx.z;
  int d = db*256 + threadIdx.x;
  float c0=cw[d*4],c1=cw[d*4+1],c2=cw[d*4+2],c3=cw[d*4+3];
  float dtw[16], bpw[16];
  #pragma unroll
  for(int s=0;s<16;s++){ dtw[s]=dtw_g[d*16+s]; bpw[s]=bpw_g[d*16+s]; }
  float bias = dtbias_g[d];
  int t0 = c*TC;
  long base = ((long)b*SEQ + t0)*(2*DI) + d;
  float wm3 = (t0>0) ? bf2f(xz[base - 3*(2*DI)]) : 0.f;
  float wm2 = (t0>0) ? bf2f(xz[base - 2*(2*DI)]) : 0.f;
  float wm1 = (t0>0) ? bf2f(xz[base - 1*(2*DI)]) : 0.f;
  const float4* dr = reinterpret_cast<const float4*>(dtb + ((long)b*SEQ + t0)*32);
  const unsigned short* xp = xz + base;
  float h = 0.f, P = 1.f;
  for(int t=0;t<TC;t++){
    float wt = bf2f(*xp); xp += 2*DI;
    float u = siluf(c0*wm3 + c1*wm2 + c2*wm1 + c3*wt);
    wm3=wm2; wm2=wm1; wm1=wt;
    float4 q0=dr[t*8+0], q1=dr[t*8+1], q2=dr[t*8+2], q3=dr[t*8+3];
    float4 p0=dr[t*8+4], p1=dr[t*8+5], p2=dr[t*8+6], p3=dr[t*8+7];
    float da = bias
      + q0.x*dtw[0]+q0.y*dtw[1]+q0.z*dtw[2]+q0.w*dtw[3]
      + q1.x*dtw[4]+q1.y*dtw[5]+q1.z*dtw[6]+q1.w*dtw[7]
      + q2.x*dtw[8]+q2.y*dtw[9]+q2.z*dtw[10]+q2.w*dtw[11]
      + q3.x*dtw[12]+q3.y*dtw[13]+q3.z*dtw[14]+q3.w*dtw[15];
    float ba =
        p0.x*bpw[0]+p0.y*bpw[1]+p0.z*bpw[2]+p0.w*bpw[3]
      + p1.x*bpw[4]+p1.y*bpw[5]+p1.z*bpw[6]+p1.w*bpw[7]
      + p2.x*bpw[8]+p2.y*bpw[9]+p2.z*bpw[10]+p2.w*bpw[11]
      + p3.x*bpw[12]+p3.y*bpw[13]+p3.z*bpw[14]+p3.w*bpw[15];
    float delta = fminf(fmaxf(softplusf(da), 1e-4f), 1.0f);
    float a = 1.0f - delta;
    h = h*a + u*ba;
    P *= a;
  }
  chunk[((long)b*DI + d)*NCHUNK + c] = make_float2(P, h);
}

// ---------------- scan pass C: combine chunk prefixes, emit y = (h + dp*u)*silu(z) (bf16) ----------------
__global__ __launch_bounds__(256) void scanC_kernel(const unsigned short* __restrict__ xz,
      const float* __restrict__ dtb, const float* __restrict__ cw,
      const float* __restrict__ dtw_g, const float* __restrict__ dtbias_g,
      const float* __restrict__ bpw_g, const float* __restrict__ dp_g,
      const float2* __restrict__ chunk, unsigned short* __restrict__ y){
  int c = blockIdx.x, db = blockIdx.y, b = blockIdx.z;
  int d = db*256 + threadIdx.x;
  float c0=cw[d*4],c1=cw[d*4+1],c2=cw[d*4+2],c3=cw[d*4+3];
  float dtw[16], bpw[16];
  #pragma unroll
  for(int s=0;s<16;s++){ dtw[s]=dtw_g[d*16+s]; bpw[s]=bpw_g[d*16+s]; }
  float bias = dtbias_g[d];
  float dp = dp_g[d];
  int t0 = c*TC;
  long base = ((long)b*SEQ + t0)*(2*DI) + d;
  float wm3 = (t0>0) ? bf2f(xz[base - 3*(2*DI)]) : 0.f;
  float wm2 = (t0>0) ? bf2f(xz[base - 2*(2*DI)]) : 0.f;
  float wm1 = (t0>0) ? bf2f(xz[base - 1*(2*DI)]) : 0.f;
  const float4* dr = reinterpret_cast<const float4*>(dtb + ((long)b*SEQ + t0)*32);
  const unsigned short* xp = xz + base;
  const unsigned short* zp = xz + base + DI;
  unsigned short* yp = y + ((long)b*SEQ + t0)*DI + d;
  float h = 0.f;
  const float2* cb = chunk + ((long)b*DI + d)*NCHUNK;
  for(int cc2=0; cc2<c; cc2++){ float2 ps = cb[cc2]; h = ps.x*h + ps.y; }
  for(int t=0;t<TC;t++){
    float wt = bf2f(*xp); xp += 2*DI;
    float u = siluf(c0*wm3 + c1*wm2 + c2*wm1 + c3*wt);
    wm3=wm2; wm2=wm1; wm1=wt;
    float4 q0=dr[t*8+0], q1=dr[t*8+1], q2=dr[t*8+2], q3=dr[t*8+3];
    float4 p0=dr[t*8+4], p1=dr[t*8+5], p2=dr[t*8+6], p3=dr[t*8+7];
    float da = bias
      + q0.x*dtw[0]+q0.y*dtw[1]+q0.z*dtw[2]+q0.w*dtw[3]
      + q1.x*dtw[4]+q1.y*dtw[5]+q1.z*dtw[6]+q1.w*dtw[7]
      + q2.x*dtw[8]+q2.y*dtw[9]+q2.z*dtw[10]+q2.w*dtw[11]
      + q3.x*dtw[12]+q3.y*dtw[13]+q3.z*dtw[14]+q3.w*dtw[15];
    float ba =
        p0.x*bpw[0]+p0.y*bpw[1]+p0.z*bpw[2]+p0.w*bpw[3]
      + p1.x*bpw[4]+p1.y*bpw[5]+p1.z*bpw[6]+p1.w*bpw[7]
      + p2.x*bpw[8]+p2.y*bpw[9]+p2.z*bpw[10]+p2.w*bpw[11]
      + p3.x*bpw[12]+p3.y*bpw[13]+p3.z*bpw[14]+p3.w*bpw[15];
    float delta = fminf(fmaxf(softplusf(da), 1e-4f), 1.0f);
    h = h*(1.0f - delta) + u*ba;
    float zv = bf2f(*zp); zp += 2*DI;
    float yv = (h + dp*u) * siluf(zv);
    *yp = f2bf(yv); yp += DI;
  }
}

// ---------------- launch ----------------
extern "C" void kernel_launch(void* const* d_in, const int* in_sizes, int n_in,
                              void* d_out, int out_size, void* d_ws, size_t ws_size,
                              hipStream_t stream){
  const int*   tokens  = (const int*)  d_in[0];
  const int*   emotion = (const int*)  d_in[1];
  const int*   style   = (const int*)  d_in[2];
  const int*   keysig  = (const int*)  d_in[3];
  const int*   modei   = (const int*)  d_in[4];
  const float* bpm     = (const float*)d_in[5];
  const float* tok_emb = (const float*)d_in[6];
  const float* emo_emb = (const float*)d_in[7];
  const float* sty_emb = (const float*)d_in[8];
  const float* key_emb = (const float*)d_in[9];
  const float* mode_emb= (const float*)d_in[10];
  const float* bpm_w   = (const float*)d_in[11];
  const float* bpm_b   = (const float*)d_in[12];
  const float* cond_w  = (const float*)d_in[13];
  const float* cond_b  = (const float*)d_in[14];
  const float* pos_emb = (const float*)d_in[15];
  const float* ln_g    = (const float*)d_in[16];
  const float* ln_b    = (const float*)d_in[17];
  const float* in_w    = (const float*)d_in[18];
  const float* conv_w  = (const float*)d_in[19];
  const float* xproj_w = (const float*)d_in[20];
  const float* dt_w    = (const float*)d_in[21];
  const float* dt_b    = (const float*)d_in[22];
  const float* bproj_w = (const float*)d_in[23];
  const float* d_param = (const float*)d_in[24];
  const float* out_w   = (const float*)d_in[25];
  const float* final_g = (const float*)d_in[26];
  const float* final_b = (const float*)d_in[27];
  const float* head_w  = (const float*)d_in[28];
  const float* head_b  = (const float*)d_in[29];

  // workspace layout (total ~204.5 MiB)
  char* ws = (char*)d_ws;
  float*          x       = (float*)(ws + 0L);                    //  50,331,648
  unsigned short* hy      = (unsigned short*)(ws + 50331648L);    //  50,331,648 (h_bf / y_bf / xfin union)
  unsigned short* xz      = (unsigned short*)(ws + 100663296L);   // 100,663,296 (bf16 [BT, 2*DI])
  float*          dtbuf   = (float*)(ws + 201326592L);            //   2,097,152
  float2*         chunk   = (float2*)(ws + 203423744L);           //   1,572,864
  float*          condv   = (float*)(ws + 204996608L);            //      24,576
  unsigned short* inwb    = (unsigned short*)(ws + 205021184L);   //   4,718,592 (per-layer)
  unsigned short* outwb   = (unsigned short*)(ws + 209739776L);   //   2,359,296 (per-layer)
  unsigned short* headwb  = (unsigned short*)(ws + 212099072L);   //     786,432
  unsigned short* wbf_all = (unsigned short*)(ws + 212885504L);   //     786,432 (bf16 xproj_w, all layers)

  unsigned short* h_bf = hy;        // [BT, DM]
  unsigned short* y_bf = hy;        // [BT, DI] (reuses same region after h consumed)
  unsigned short* xfin = hy;        // [BT, DM] final LN output

  cvt_bf16_kernel<<<128,256,0,stream>>>((const float4*)head_w,(ushort4*)headwb, NVOCAB*DM/4);
  cvt_bf16_kernel<<<384,256,0,stream>>>((const float4*)xproj_w,(ushort4*)wbf_all, NL*32*DI/4);
  cond_kernel<<<dim3(48,8),256,0,stream>>>(emotion, style, keysig, modei, bpm, emo_emb, sty_emb,
        key_emb, mode_emb, bpm_w, bpm_b, cond_w, cond_b, condv);
  embed_kernel<<<BT,192,0,stream>>>(tokens, tok_emb, condv, pos_emb, x);

  for(int l=0; l<NL; l++){
    cvt_bf16_kernel<<<1024,256,0,stream>>>((const float4*)(in_w  + (long)l*2*DI*DM), (ushort4*)inwb,  2*DI*DM/4);
    cvt_bf16_kernel<<<512, 256,0,stream>>>((const float4*)(out_w + (long)l*DM*DI),   (ushort4*)outwb, DM*DI/4);
    ln_bf16_kernel<<<BT/4,256,0,stream>>>(x, ln_g + l*DM, ln_b + l*DM, h_bf);
    gemm_lds<3><<<dim3(2*DI/128, BT/128),256,0,stream>>>(h_bf, inwb, xz, nullptr, DM, 2*DI);
    xproj_kernel<<<BT/16,256,0,stream>>>(xz, conv_w + l*DI*4, wbf_all + (long)l*32*DI, dtbuf);
    scanA_kernel<<<dim3(NCHUNK,6,BATCH),256,0,stream>>>(xz, dtbuf, conv_w + l*DI*4,
          dt_w + l*DI*DS, dt_b + l*DI, bproj_w + l*DI*DS, chunk);
    scanC_kernel<<<dim3(NCHUNK,6,BATCH),256,0,stream>>>(xz, dtbuf, conv_w + l*DI*4,
          dt_w + l*DI*DS, dt_b + l*DI, bproj_w + l*DI*DS, d_param + l*DI, chunk, y_bf);
    gemm_lds<1><<<dim3(DM/128, BT/128),256,0,stream>>>(y_bf, outwb, x, nullptr, DI, DM);
  }
  ln_bf16_kernel<<<BT/4,256,0,stream>>>(x, final_g, final_b, xfin);
  gemm_lds<2><<<dim3(NVOCAB/128, BT/128),256,0,stream>>>(xfin, headwb, d_out, head_b, DM, NVOCAB);
}

// Round 4
// 4026.140 us; speedup vs baseline: 1.8145x; 1.2385x over previous
//
#include <hip/hip_runtime.h>
#include <cstdint>

#define BATCH 8
#define SEQ   2048
#define DM    768
#define DI    1536
#define DS    16
#define NL    8
#define NVOCAB 512
#define BT    (BATCH*SEQ)      // 16384
#define NCHUNK 32
#define TC    (SEQ/NCHUNK)     // 64

typedef __attribute__((ext_vector_type(8))) short bf16x8;
typedef __attribute__((ext_vector_type(4))) float f32x4;

__device__ __forceinline__ unsigned short f2bf(float f){
  unsigned int u = __float_as_uint(f);
  u += 0x7fffu + ((u >> 16) & 1u);
  return (unsigned short)(u >> 16);
}
__device__ __forceinline__ float bf2f(unsigned short s){
  return __uint_as_float(((unsigned int)s) << 16);
}
__device__ __forceinline__ float sigm(float x){ return 1.0f/(1.0f + __expf(-x)); }
__device__ __forceinline__ float siluf(float x){ return x * sigm(x); }
__device__ __forceinline__ float fast_softplus(float x){
  return (x > 15.0f) ? x : __logf(1.0f + __expf(x));
}
__device__ __forceinline__ void async16(void* l, const void* g){
  __builtin_amdgcn_global_load_lds(
      (const __attribute__((address_space(1))) unsigned int*)g,
      (__attribute__((address_space(3))) unsigned int*)l, 16, 0, 0);
}
__device__ __forceinline__ float dot4(f32x4 a, f32x4 b){
  return fmaf(a[0],b[0], fmaf(a[1],b[1], fmaf(a[2],b[2], a[3]*b[3])));
}

// ---------------- weight conversion ----------------
__global__ void cvt_bf16_kernel(const float4* __restrict__ in, ushort4* __restrict__ out, int n4){
  int i = blockIdx.x*256 + threadIdx.x;
  int stride = gridDim.x*256;
  for(; i<n4; i+=stride){
    float4 v = in[i];
    ushort4 o; o.x=f2bf(v.x); o.y=f2bf(v.y); o.z=f2bf(v.z); o.w=f2bf(v.w);
    out[i]=o;
  }
}

// ---------------- conditioning ----------------
__global__ __launch_bounds__(256) void cond_kernel(const int* __restrict__ emotion,
    const int* __restrict__ style, const int* __restrict__ keysig, const int* __restrict__ modei,
    const float* __restrict__ bpm, const float* __restrict__ emo_emb, const float* __restrict__ sty_emb,
    const float* __restrict__ key_emb, const float* __restrict__ mode_emb,
    const float* __restrict__ bpm_w, const float* __restrict__ bpm_b,
    const float* __restrict__ cond_w, const float* __restrict__ cond_b,
    float* __restrict__ cond_out){
  int b = blockIdx.y;
  __shared__ float vec[5*DM];
  int e = emotion[b], st = style[b], ks = keysig[b], md = modei[b];
  float bp = bpm[b];
  for(int j=threadIdx.x; j<5*DM; j+=256){
    int seg = j/DM, off = j - seg*DM;
    float v;
    if(seg==0)      v = emo_emb[e*DM+off];
    else if(seg==1) v = sty_emb[st*DM+off];
    else if(seg==2) v = key_emb[ks*DM+off];
    else if(seg==3) v = mode_emb[md*DM+off];
    else            v = bp*bpm_w[off] + bpm_b[off];
    vec[j] = v;
  }
  __syncthreads();
  int wid = threadIdx.x>>6, lane = threadIdx.x&63;
  #pragma unroll
  for(int i=0;i<4;i++){
    int dm = blockIdx.x*16 + wid*4 + i;
    const float* w = cond_w + (long)dm*(5*DM);
    float acc = 0.f;
    for(int j=lane; j<5*DM; j+=64) acc += vec[j]*w[j];
    #pragma unroll
    for(int off=32; off>0; off>>=1) acc += __shfl_xor(acc, off);
    if(lane==0) cond_out[b*DM + dm] = acc + cond_b[dm];
  }
}

// x = tok_emb[tokens] + cond + pos_emb
__global__ void embed_kernel(const int* __restrict__ tokens, const float* __restrict__ tok_emb,
    const float* __restrict__ cond, const float* __restrict__ pos_emb, float* __restrict__ x){
  int bt = blockIdx.x;
  int b = bt >> 11, t = bt & 2047;
  int tok = tokens[bt];
  const float4* te = reinterpret_cast<const float4*>(tok_emb + (long)tok*DM);
  const float4* ce = reinterpret_cast<const float4*>(cond + (long)b*DM);
  const float4* pe = reinterpret_cast<const float4*>(pos_emb + (long)t*DM);
  float4* xo = reinterpret_cast<float4*>(x + (long)bt*DM);
  int i = threadIdx.x;  // 0..191
  float4 a = te[i], c = ce[i], p = pe[i];
  xo[i] = make_float4(a.x+c.x+p.x, a.y+c.y+p.y, a.z+c.z+p.z, a.w+c.w+p.w);
}

// ---------------- layernorm -> bf16 ----------------
__global__ __launch_bounds__(256) void ln_bf16_kernel(const float* __restrict__ x,
                     const float* __restrict__ g, const float* __restrict__ bta,
                     unsigned short* __restrict__ out){
  int row  = blockIdx.x*4 + (threadIdx.x >> 6);
  int lane = threadIdx.x & 63;
  const float* xr = x + (long)row*DM;
  float4 v[3];
  float sum=0.f, sq=0.f;
  #pragma unroll
  for(int i=0;i<3;i++){
    v[i] = *reinterpret_cast<const float4*>(xr + i*256 + lane*4);
    sum += v[i].x + v[i].y + v[i].z + v[i].w;
    sq  += v[i].x*v[i].x + v[i].y*v[i].y + v[i].z*v[i].z + v[i].w*v[i].w;
  }
  #pragma unroll
  for(int off=32; off>0; off>>=1){
    sum += __shfl_xor(sum, off);
    sq  += __shfl_xor(sq , off);
  }
  float mu  = sum * (1.0f/DM);
  float var = sq  * (1.0f/DM) - mu*mu;
  float rs  = rsqrtf(var + 1e-5f);
  unsigned short* orow = out + (long)row*DM;
  #pragma unroll
  for(int i=0;i<3;i++){
    int d = i*256 + lane*4;
    float4 gg = *reinterpret_cast<const float4*>(g + d);
    float4 bb = *reinterpret_cast<const float4*>(bta + d);
    ushort4 o;
    o.x = f2bf((v[i].x - mu)*rs*gg.x + bb.x);
    o.y = f2bf((v[i].y - mu)*rs*gg.y + bb.y);
    o.z = f2bf((v[i].z - mu)*rs*gg.z + bb.z);
    o.w = f2bf((v[i].w - mu)*rs*gg.w + bb.w);
    *reinterpret_cast<ushort4*>(orow + d) = o;
  }
}

// ---------------- LDS-staged GEMM (m97 structure): C[M,N] = A[M,K](bf16) * B[N,K](bf16)^T
// MODE 0: f32 C = acc ; MODE 1: f32 C += acc ; MODE 2: f32 C = acc + bias[col] ; MODE 3: bf16 C = acc
template<int MODE>
__global__ __launch_bounds__(256) void gemm_lds(const unsigned short* __restrict__ A,
                                               const unsigned short* __restrict__ B,
                                               void* __restrict__ Cv,
                                               const float* __restrict__ bias,
                                               int K, int ldc){
  __shared__ short As[128*32];   // 8 KiB
  __shared__ short Bs[128*32];   // 8 KiB
  const short* Ap = (const short*)A;
  const short* Bp = (const short*)B;
  int tid  = threadIdx.x;
  int lane = tid & 63;
  int wid  = tid >> 6;
  int row0 = blockIdx.y*128;
  int col0 = blockIdx.x*128;

  int ar = tid >> 2;
  int ac = (tid & 3) * 8;
  const short* Ag0 = Ap + (long)(row0 + ar     )*K + ac;
  const short* Ag1 = Ap + (long)(row0 + ar + 64)*K + ac;
  const short* Bg0 = Bp + (long)(col0 + ar     )*K + ac;
  const short* Bg1 = Bp + (long)(col0 + ar + 64)*K + ac;
  char* lA0 = (char*)As + tid*16;
  char* lA1 = (char*)As + (256 + tid)*16;
  char* lB0 = (char*)Bs + tid*16;
  char* lB1 = (char*)Bs + (256 + tid)*16;

  int wr = (wid>>1)*64;
  int wc = (wid&1)*64;
  int fr = lane & 15;
  int fk = (lane >> 4) << 3;

  f32x4 acc[4][4];
  #pragma unroll
  for(int m=0;m<4;m++)
    #pragma unroll
    for(int n=0;n<4;n++)
      acc[m][n] = (f32x4){0.f,0.f,0.f,0.f};

  for(int kt=0; kt<K; kt+=32){
    async16(lA0, Ag0 + kt);
    async16(lA1, Ag1 + kt);
    async16(lB0, Bg0 + kt);
    async16(lB1, Bg1 + kt);
    __syncthreads();
    bf16x8 av[4], bv[4];
    #pragma unroll
    for(int m=0;m<4;m++)
      av[m] = *reinterpret_cast<const bf16x8*>(As + (wr + m*16 + fr)*32 + fk);
    #pragma unroll
    for(int n=0;n<4;n++)
      bv[n] = *reinterpret_cast<const bf16x8*>(Bs + (wc + n*16 + fr)*32 + fk);
    #pragma unroll
    for(int m=0;m<4;m++)
      #pragma unroll
      for(int n=0;n<4;n++)
        acc[m][n] = __builtin_amdgcn_mfma_f32_16x16x32_bf16(av[m], bv[n], acc[m][n], 0, 0, 0);
    __syncthreads();
  }

  int rr = (lane >> 4) << 2;
  int cc = lane & 15;
  #pragma unroll
  for(int m=0;m<4;m++){
    #pragma unroll
    for(int n=0;n<4;n++){
      int col = col0 + wc + n*16 + cc;
      #pragma unroll
      for(int i=0;i<4;i++){
        long idx = (long)(row0 + wr + m*16 + rr + i)*ldc + col;
        float v = acc[m][n][i];
        if(MODE==3)      ((unsigned short*)Cv)[idx] = f2bf(v);
        else if(MODE==1) ((float*)Cv)[idx] += v;
        else if(MODE==2) ((float*)Cv)[idx] = v + bias[col];
        else             ((float*)Cv)[idx] = v;
      }
    }
  }
}

// ---------------- fused conv+silu+xproj: xz(bf16) -> dtb_raw [BT,32](f32) ----------------
__global__ __launch_bounds__(256) void xproj_kernel(const unsigned short* __restrict__ xz,
      const float* __restrict__ cw, const unsigned short* __restrict__ wbf,
      float* __restrict__ dtb){
  __shared__ unsigned short xcs[16][DI];   // 48 KiB
  int blk = blockIdx.x;
  int b  = blk >> 7;
  int t0 = (blk & 127) << 4;
  int tid = threadIdx.x;
  long base = ((long)b*SEQ + t0)*(2*DI);
  if(tid < 192){
    int d0 = tid*8;
    float cc0[8], cc1[8], cc2[8], cc3[8];
    #pragma unroll
    for(int j=0;j<8;j++){
      cc0[j]=cw[(d0+j)*4+0]; cc1[j]=cw[(d0+j)*4+1];
      cc2[j]=cw[(d0+j)*4+2]; cc3[j]=cw[(d0+j)*4+3];
    }
    float wm3[8], wm2[8], wm1[8];
    #pragma unroll
    for(int j=0;j<8;j++){ wm3[j]=0.f; wm2[j]=0.f; wm1[j]=0.f; }
    if(t0>0){
      bf16x8 v3 = *reinterpret_cast<const bf16x8*>(xz + base - 3*(2*DI) + d0);
      bf16x8 v2 = *reinterpret_cast<const bf16x8*>(xz + base - 2*(2*DI) + d0);
      bf16x8 v1 = *reinterpret_cast<const bf16x8*>(xz + base - 1*(2*DI) + d0);
      #pragma unroll
      for(int j=0;j<8;j++){
        wm3[j]=bf2f((unsigned short)v3[j]);
        wm2[j]=bf2f((unsigned short)v2[j]);
        wm1[j]=bf2f((unsigned short)v1[j]);
      }
    }
    for(int tt=0; tt<16; tt++){
      bf16x8 vt = *reinterpret_cast<const bf16x8*>(xz + base + (long)tt*(2*DI) + d0);
      bf16x8 o;
      #pragma unroll
      for(int j=0;j<8;j++){
        float wt = bf2f((unsigned short)vt[j]);
        float u  = cc0[j]*wm3[j] + cc1[j]*wm2[j] + cc2[j]*wm1[j] + cc3[j]*wt;
        o[j] = (short)f2bf(siluf(u));
        wm3[j]=wm2[j]; wm2[j]=wm1[j]; wm1[j]=wt;
      }
      *reinterpret_cast<bf16x8*>(&xcs[tt][d0]) = o;
    }
  }
  __syncthreads();
  int s  = tid & 31;
  int th = tid >> 5;     // 0..7 -> rows th and th+8
  const unsigned short* wrow = wbf + (long)s*DI;
  float acc0 = 0.f, acc1 = 0.f;
  for(int dc=0; dc<DI; dc+=8){
    bf16x8 w8 = *reinterpret_cast<const bf16x8*>(wrow + dc);
    bf16x8 a0 = *reinterpret_cast<const bf16x8*>(&xcs[th][dc]);
    bf16x8 a1 = *reinterpret_cast<const bf16x8*>(&xcs[th+8][dc]);
    #pragma unroll
    for(int j=0;j<8;j++){
      float wv = bf2f((unsigned short)w8[j]);
      acc0 += bf2f((unsigned short)a0[j])*wv;
      acc1 += bf2f((unsigned short)a1[j])*wv;
    }
  }
  dtb[((long)b*SEQ + t0 + th    )*32 + s] = acc0;
  dtb[((long)b*SEQ + t0 + th + 8)*32 + s] = acc1;
}

// ---------------- scan pass A: per-chunk (P = prod(1-delta), S = local h) ----------------
__global__ __launch_bounds__(256) void scanA_kernel(const unsigned short* __restrict__ xz,
      const float* __restrict__ dtb, const float* __restrict__ cw,
      const float* __restrict__ dtw_g, const float* __restrict__ dtbias_g,
      const float* __restrict__ bpw_g, float2* __restrict__ chunk){
  __shared__ float dsb[TC*32];        // 8 KiB: dtb rows for this chunk
  int c = blockIdx.x, db = blockIdx.y, b = blockIdx.z;
  int d = db*256 + threadIdx.x;
  int t0 = c*TC;
  {
    const float4* src = reinterpret_cast<const float4*>(dtb + ((long)b*SEQ + t0)*32);
    float4* dst = reinterpret_cast<float4*>(dsb);
    dst[threadIdx.x]       = src[threadIdx.x];
    dst[threadIdx.x + 256] = src[threadIdx.x + 256];
  }
  float c0=cw[d*4],c1=cw[d*4+1],c2=cw[d*4+2],c3=cw[d*4+3];
  f32x4 wq0 = *reinterpret_cast<const f32x4*>(dtw_g + d*16 + 0);
  f32x4 wq1 = *reinterpret_cast<const f32x4*>(dtw_g + d*16 + 4);
  f32x4 wq2 = *reinterpret_cast<const f32x4*>(dtw_g + d*16 + 8);
  f32x4 wq3 = *reinterpret_cast<const f32x4*>(dtw_g + d*16 + 12);
  f32x4 wp0 = *reinterpret_cast<const f32x4*>(bpw_g + d*16 + 0);
  f32x4 wp1 = *reinterpret_cast<const f32x4*>(bpw_g + d*16 + 4);
  f32x4 wp2 = *reinterpret_cast<const f32x4*>(bpw_g + d*16 + 8);
  f32x4 wp3 = *reinterpret_cast<const f32x4*>(bpw_g + d*16 + 12);
  float bias = dtbias_g[d];
  // pin in registers: opaque def prevents rematerialized per-iter reloads
  asm volatile("" : "+v"(wq0),"+v"(wq1),"+v"(wq2),"+v"(wq3),
                    "+v"(wp0),"+v"(wp1),"+v"(wp2),"+v"(wp3),
                    "+v"(c0),"+v"(c1),"+v"(c2),"+v"(c3),"+v"(bias));
  long base = ((long)b*SEQ + t0)*(2*DI) + d;
  float wm3 = (t0>0) ? bf2f(xz[base - 3*(2*DI)]) : 0.f;
  float wm2 = (t0>0) ? bf2f(xz[base - 2*(2*DI)]) : 0.f;
  float wm1 = (t0>0) ? bf2f(xz[base - 1*(2*DI)]) : 0.f;
  const unsigned short* xp = xz + base;
  __syncthreads();
  float h = 0.f, P = 1.f;
  for(int t=0;t<TC;t++){
    float wt = bf2f(*xp); xp += 2*DI;
    float u = siluf(fmaf(c3,wt, fmaf(c2,wm1, fmaf(c1,wm2, c0*wm3))));
    wm3=wm2; wm2=wm1; wm1=wt;
    const f32x4* row = reinterpret_cast<const f32x4*>(dsb + t*32);
    float da = bias + dot4(row[0],wq0) + dot4(row[1],wq1) + dot4(row[2],wq2) + dot4(row[3],wq3);
    float ba =        dot4(row[4],wp0) + dot4(row[5],wp1) + dot4(row[6],wp2) + dot4(row[7],wp3);
    float delta = fminf(fmaxf(fast_softplus(da), 1e-4f), 1.0f);
    float a = 1.0f - delta;
    h = fmaf(h, a, u*ba);
    P *= a;
  }
  chunk[((long)b*DI + d)*NCHUNK + c] = make_float2(P, h);
}

// ---------------- scan pass C: combine chunk prefixes, emit y = (h + dp*u)*silu(z) (bf16) ----------------
__global__ __launch_bounds__(256) void scanC_kernel(const unsigned short* __restrict__ xz,
      const float* __restrict__ dtb, const float* __restrict__ cw,
      const float* __restrict__ dtw_g, const float* __restrict__ dtbias_g,
      const float* __restrict__ bpw_g, const float* __restrict__ dp_g,
      const float2* __restrict__ chunk, unsigned short* __restrict__ y){
  __shared__ float dsb[TC*32];        // 8 KiB
  int c = blockIdx.x, db = blockIdx.y, b = blockIdx.z;
  int d = db*256 + threadIdx.x;
  int t0 = c*TC;
  {
    const float4* src = reinterpret_cast<const float4*>(dtb + ((long)b*SEQ + t0)*32);
    float4* dst = reinterpret_cast<float4*>(dsb);
    dst[threadIdx.x]       = src[threadIdx.x];
    dst[threadIdx.x + 256] = src[threadIdx.x + 256];
  }
  float c0=cw[d*4],c1=cw[d*4+1],c2=cw[d*4+2],c3=cw[d*4+3];
  f32x4 wq0 = *reinterpret_cast<const f32x4*>(dtw_g + d*16 + 0);
  f32x4 wq1 = *reinterpret_cast<const f32x4*>(dtw_g + d*16 + 4);
  f32x4 wq2 = *reinterpret_cast<const f32x4*>(dtw_g + d*16 + 8);
  f32x4 wq3 = *reinterpret_cast<const f32x4*>(dtw_g + d*16 + 12);
  f32x4 wp0 = *reinterpret_cast<const f32x4*>(bpw_g + d*16 + 0);
  f32x4 wp1 = *reinterpret_cast<const f32x4*>(bpw_g + d*16 + 4);
  f32x4 wp2 = *reinterpret_cast<const f32x4*>(bpw_g + d*16 + 8);
  f32x4 wp3 = *reinterpret_cast<const f32x4*>(bpw_g + d*16 + 12);
  float bias = dtbias_g[d];
  float dp = dp_g[d];
  asm volatile("" : "+v"(wq0),"+v"(wq1),"+v"(wq2),"+v"(wq3),
                    "+v"(wp0),"+v"(wp1),"+v"(wp2),"+v"(wp3),
                    "+v"(c0),"+v"(c1),"+v"(c2),"+v"(c3),"+v"(bias),"+v"(dp));
  long base = ((long)b*SEQ + t0)*(2*DI) + d;
  float wm3 = (t0>0) ? bf2f(xz[base - 3*(2*DI)]) : 0.f;
  float wm2 = (t0>0) ? bf2f(xz[base - 2*(2*DI)]) : 0.f;
  float wm1 = (t0>0) ? bf2f(xz[base - 1*(2*DI)]) : 0.f;
  const unsigned short* xp = xz + base;
  const unsigned short* zp = xz + base + DI;
  unsigned short* yp = y + ((long)b*SEQ + t0)*DI + d;
  float h = 0.f;
  const float2* cb = chunk + ((long)b*DI + d)*NCHUNK;
  for(int cc2=0; cc2<c; cc2++){ float2 ps = cb[cc2]; h = ps.x*h + ps.y; }
  __syncthreads();
  for(int t=0;t<TC;t++){
    float wt = bf2f(*xp); xp += 2*DI;
    float u = siluf(fmaf(c3,wt, fmaf(c2,wm1, fmaf(c1,wm2, c0*wm3))));
    wm3=wm2; wm2=wm1; wm1=wt;
    const f32x4* row = reinterpret_cast<const f32x4*>(dsb + t*32);
    float da = bias + dot4(row[0],wq0) + dot4(row[1],wq1) + dot4(row[2],wq2) + dot4(row[3],wq3);
    float ba =        dot4(row[4],wp0) + dot4(row[5],wp1) + dot4(row[6],wp2) + dot4(row[7],wp3);
    float delta = fminf(fmaxf(fast_softplus(da), 1e-4f), 1.0f);
    h = fmaf(h, 1.0f - delta, u*ba);
    float zv = bf2f(*zp); zp += 2*DI;
    float yv = (h + dp*u) * siluf(zv);
    *yp = f2bf(yv); yp += DI;
  }
}

// ---------------- launch ----------------
extern "C" void kernel_launch(void* const* d_in, const int* in_sizes, int n_in,
                              void* d_out, int out_size, void* d_ws, size_t ws_size,
                              hipStream_t stream){
  const int*   tokens  = (const int*)  d_in[0];
  const int*   emotion = (const int*)  d_in[1];
  const int*   style   = (const int*)  d_in[2];
  const int*   keysig  = (const int*)  d_in[3];
  const int*   modei   = (const int*)  d_in[4];
  const float* bpm     = (const float*)d_in[5];
  const float* tok_emb = (const float*)d_in[6];
  const float* emo_emb = (const float*)d_in[7];
  const float* sty_emb = (const float*)d_in[8];
  const float* key_emb = (const float*)d_in[9];
  const float* mode_emb= (const float*)d_in[10];
  const float* bpm_w   = (const float*)d_in[11];
  const float* bpm_b   = (const float*)d_in[12];
  const float* cond_w  = (const float*)d_in[13];
  const float* cond_b  = (const float*)d_in[14];
  const float* pos_emb = (const float*)d_in[15];
  const float* ln_g    = (const float*)d_in[16];
  const float* ln_b    = (const float*)d_in[17];
  const float* in_w    = (const float*)d_in[18];
  const float* conv_w  = (const float*)d_in[19];
  const float* xproj_w = (const float*)d_in[20];
  const float* dt_w    = (const float*)d_in[21];
  const float* dt_b    = (const float*)d_in[22];
  const float* bproj_w = (const float*)d_in[23];
  const float* d_param = (const float*)d_in[24];
  const float* out_w   = (const float*)d_in[25];
  const float* final_g = (const float*)d_in[26];
  const float* final_b = (const float*)d_in[27];
  const float* head_w  = (const float*)d_in[28];
  const float* head_b  = (const float*)d_in[29];

  // workspace layout (total ~206.8 MiB)
  char* ws = (char*)d_ws;
  float*          x       = (float*)(ws + 0L);                    //  50,331,648
  unsigned short* hy      = (unsigned short*)(ws + 50331648L);    //  50,331,648 (h_bf / y_bf / xfin union)
  unsigned short* xz      = (unsigned short*)(ws + 100663296L);   // 100,663,296 (bf16 [BT, 2*DI])
  float*          dtbuf   = (float*)(ws + 201326592L);            //   2,097,152
  float2*         chunk   = (float2*)(ws + 203423744L);           //   3,145,728 (NCHUNK=32)
  float*          condv   = (float*)(ws + 206569472L);            //      24,576
  unsigned short* inwb    = (unsigned short*)(ws + 206594048L);   //   4,718,592 (per-layer)
  unsigned short* outwb   = (unsigned short*)(ws + 211312640L);   //   2,359,296 (per-layer)
  unsigned short* headwb  = (unsigned short*)(ws + 213671936L);   //     786,432
  unsigned short* wbf_all = (unsigned short*)(ws + 214458368L);   //     786,432 (bf16 xproj_w, all layers)

  unsigned short* h_bf = hy;        // [BT, DM]
  unsigned short* y_bf = hy;        // [BT, DI] (reuses same region after h consumed)
  unsigned short* xfin = hy;        // [BT, DM] final LN output

  cvt_bf16_kernel<<<128,256,0,stream>>>((const float4*)head_w,(ushort4*)headwb, NVOCAB*DM/4);
  cvt_bf16_kernel<<<384,256,0,stream>>>((const float4*)xproj_w,(ushort4*)wbf_all, NL*32*DI/4);
  cond_kernel<<<dim3(48,8),256,0,stream>>>(emotion, style, keysig, modei, bpm, emo_emb, sty_emb,
        key_emb, mode_emb, bpm_w, bpm_b, cond_w, cond_b, condv);
  embed_kernel<<<BT,192,0,stream>>>(tokens, tok_emb, condv, pos_emb, x);

  for(int l=0; l<NL; l++){
    cvt_bf16_kernel<<<1024,256,0,stream>>>((const float4*)(in_w  + (long)l*2*DI*DM), (ushort4*)inwb,  2*DI*DM/4);
    cvt_bf16_kernel<<<512, 256,0,stream>>>((const float4*)(out_w + (long)l*DM*DI),   (ushort4*)outwb, DM*DI/4);
    ln_bf16_kernel<<<BT/4,256,0,stream>>>(x, ln_g + l*DM, ln_b + l*DM, h_bf);
    gemm_lds<3><<<dim3(2*DI/128, BT/128),256,0,stream>>>(h_bf, inwb, xz, nullptr, DM, 2*DI);
    xproj_kernel<<<BT/16,256,0,stream>>>(xz, conv_w + l*DI*4, wbf_all + (long)l*32*DI, dtbuf);
    scanA_kernel<<<dim3(NCHUNK,6,BATCH),256,0,stream>>>(xz, dtbuf, conv_w + l*DI*4,
          dt_w + l*DI*DS, dt_b + l*DI, bproj_w + l*DI*DS, chunk);
    scanC_kernel<<<dim3(NCHUNK,6,BATCH),256,0,stream>>>(xz, dtbuf, conv_w + l*DI*4,
          dt_w + l*DI*DS, dt_b + l*DI, bproj_w + l*DI*DS, d_param + l*DI, chunk, y_bf);
    gemm_lds<1><<<dim3(DM/128, BT/128),256,0,stream>>>(y_bf, outwb, x, nullptr, DI, DM);
  }
  ln_bf16_kernel<<<BT/4,256,0,stream>>>(x, final_g, final_b, xfin);
  gemm_lds<2><<<dim3(NVOCAB/128, BT/128),256,0,stream>>>(xfin, headwb, d_out, head_b, DM, NVOCAB);
}